// Round 12
// baseline (685.026 us; speedup 1.0000x reference)
//
#include <hip/hip_runtime.h>
#include <stdint.h>

#define TFAC 0.05f
#define BM 256
#define BN 128
#define BK 64
#define XCLIP 6.0f
#define SX (XCLIP / 127.0f)

typedef __attribute__((ext_vector_type(4))) int i32x4;

#define AS1(p) ((const __attribute__((address_space(1))) void*)(p))
#define AS3(p) ((__attribute__((address_space(3))) void*)(p))
#define SB0() __builtin_amdgcn_sched_barrier(0)

static __device__ __forceinline__ unsigned pack4(int b0, int b1, int b2, int b3) {
  return (unsigned)(unsigned char)b0 | ((unsigned)(unsigned char)b1 << 8) |
         ((unsigned)(unsigned char)b2 << 16) | ((unsigned)(unsigned char)b3 << 24);
}

// ---- weight quantization -> ternary i8 in MFMA FRAGMENT ORDER + f32 scale ----
// B'[n>>4][k>>6][lane][16B], lane = (n&15) + 16*kchunk, kchunk = (k>>4)&3.
__global__ __launch_bounds__(256) void quant_kernel(
    const float* __restrict__ W, uint4* __restrict__ T,
    float* __restrict__ scale, int IN) {
  const int row = blockIdx.x;
  const int t = threadIdx.x;
  const float4* wr = reinterpret_cast<const float4*>(W + (size_t)row * IN);

  // thread t holds k in [t*16, t*16+16): contiguous 16 elements
  float4 v[4];
  float s = 0.f;
#pragma unroll
  for (int i = 0; i < 4; ++i) {
    v[i] = wr[t * 4 + i];
    s += fabsf(v[i].x) + fabsf(v[i].y) + fabsf(v[i].z) + fabsf(v[i].w);
  }
#pragma unroll
  for (int off = 1; off < 64; off <<= 1) s += __shfl_xor(s, off);
  __shared__ float red[4];
  if ((t & 63) == 0) red[t >> 6] = s;
  __syncthreads();
  const float tot = red[0] + red[1] + red[2] + red[3];
  const float thr = TFAC * tot / (float)IN;

  float cnt = 0.f, ms = 0.f;
  unsigned u[4];
#pragma unroll
  for (int i = 0; i < 4; ++i) {
    float e[4] = {v[i].x, v[i].y, v[i].z, v[i].w};
    int o[4];
#pragma unroll
    for (int j = 0; j < 4; ++j) {
      const float a = fabsf(e[j]);
      const bool m = a > thr;
      cnt += m ? 1.f : 0.f;
      ms += m ? a : 0.f;
      o[j] = m ? (e[j] > 0.f ? 1 : -1) : 0;
    }
    u[i] = pack4(o[0], o[1], o[2], o[3]);
  }
  // fragment-order write: one 16B store
  const int k64 = IN >> 6;
  const size_t idx = ((size_t)(row >> 4) * k64 + (t >> 2)) * 64 +
                     (size_t)(((t & 3) << 4) + (row & 15));
  T[idx] = make_uint4(u[0], u[1], u[2], u[3]);

#pragma unroll
  for (int off = 1; off < 64; off <<= 1) {
    cnt += __shfl_xor(cnt, off);
    ms += __shfl_xor(ms, off);
  }
  __shared__ float rc[4], rm[4];
  if ((t & 63) == 0) { rc[t >> 6] = cnt; rm[t >> 6] = ms; }
  __syncthreads();
  if (t == 0) {
    const float c = rc[0] + rc[1] + rc[2] + rc[3];
    const float m = rm[0] + rm[1] + rm[2] + rm[3];
    scale[row] = m / fmaxf(c, 1.f);
  }
}

// ---------------- x f32 -> i8 (global scale), row-major ----------------
__global__ __launch_bounds__(256) void cvt_kernel(
    const float* __restrict__ X, unsigned* __restrict__ X8, size_t n4) {
  const size_t base = ((size_t)blockIdx.x * 256) * 4;
  const int t = threadIdx.x;
  const float inv = 127.0f / XCLIP;
#pragma unroll
  for (int i = 0; i < 4; ++i) {
    const size_t idx = base + (size_t)i * 256 + t;
    if (idx >= n4) return;
    const float4 a = reinterpret_cast<const float4*>(X)[idx];
    int b[4];
    b[0] = (int)rintf(fminf(fmaxf(a.x * inv, -127.f), 127.f));
    b[1] = (int)rintf(fminf(fmaxf(a.y * inv, -127.f), 127.f));
    b[2] = (int)rintf(fminf(fmaxf(a.z * inv, -127.f), 127.f));
    b[3] = (int)rintf(fminf(fmaxf(a.w * inv, -127.f), 127.f));
    X8[idx] = pack4(b[0], b[1], b[2], b[3]);
  }
}

// ---- 256x128 i8 NT GEMM: A via LDS (triple-buf), B direct from fragment-
// ---- order global (reg double-buf), counted vmcnt, 2 blocks/CU ----
static __device__ __forceinline__ i32x4 lds_rd(
    const signed char* buf, int grow, int lg) {
  const int rp = grow >> 1;
  const int c = (((grow & 1) << 2) + lg) ^ (rp & 7);
  return *reinterpret_cast<const i32x4*>(buf + rp * 128 + c * 16);
}

__global__ __launch_bounds__(256, 2) void gemm_kernel(
    const signed char* __restrict__ A,    // x i8 [M][K] row-major
    const i32x4* __restrict__ Bq,         // tern i8, fragment order
    const float* __restrict__ scale,      // [N]
    const float* __restrict__ bias,       // [N]
    float* __restrict__ C,                // [M][N]
    int M, int N, int K) {
  __shared__ signed char lds[3 * 16384];  // 3 A slots (256 x 64 B each)

  const int tid = (int)threadIdx.x;
  const int lane = tid & 63;
  const int w = tid >> 6;   // 0..3
  const int wm = w >> 1;    // 0..1 : 128-row half
  const int wn = w & 1;     // 0..1 : 64-col half
  const int lr = lane & 15;
  const int lg = lane >> 4;

  // XCD swizzle with intra-XCD 8-wide bn bands (r9/r11-verified)
  const int nbm = M / BM;             // 32
  const int nbn = N / BN;             // 128
  const int nwg = nbm * nbn;
  const int jpx = nwg >> 3;
  const int rows8 = nbm * 8;
  const int nband = jpx / rows8;
  const int bid = (int)blockIdx.x;
  const int xcd = bid & 7;
  const int j = bid >> 3;
  const int band = j / rows8;
  const int r = j % rows8;
  const int bm = r >> 3;
  const int bn = (xcd * nband + band) * 8 + (r & 7);
  const size_t rowA0 = (size_t)bm * BM;
  const size_t rowB0 = (size_t)bn * BN;

  const int NKT = K / BK;             // 64

  // A stage addressing (r9-proven): chunk ci -> LDS row-pair ci>>3, chunk ci&7;
  // swizzled source sc=(ci&7)^((ci>>3)&7) -> grow 2*(ci>>3)+(sc>>2), kb (sc&3)*16
  const int ci = tid;
  const int sc = (ci & 7) ^ ((ci >> 3) & 7);
  const size_t gr = (size_t)(2 * (ci >> 3) + (sc >> 2));
  const int kb = (sc & 3) * 16;
  const size_t strideRow = (size_t)64 * (size_t)K;
  const signed char* pA0 = A + (rowA0 + gr) * (size_t)K + kb;
  const int d0 = ci * 16;

  // B fragment base: frag nb = bn*8 + wn*4 + g, element = (nb*NKT + kt)*64 + lane
  const i32x4* Bf = Bq + ((size_t)(bn * 8 + wn * 4) * NKT) * 64 + lane;

#define STAGE(SLOT, KOFF)                                                      \
  _Pragma("unroll") for (int i = 0; i < 4; ++i)                                \
      __builtin_amdgcn_global_load_lds(                                        \
          AS1(pA0 + (size_t)i * strideRow + (KOFF)),                           \
          AS3((SLOT) + d0 + i * 4096), 16, 0, 0);

#define RDF(AR, SLOT)                                                          \
  _Pragma("unroll") for (int f = 0; f < 8; ++f)                                \
      AR[f] = lds_rd((SLOT), wm * 128 + f * 16 + lr, lg);

#define LDB(BR, KT)                                                            \
  _Pragma("unroll") for (int g = 0; g < 4; ++g)                                \
      BR[g] = Bf[((size_t)g * NKT + (size_t)(KT)) * 64];

#define MM(AR, BR)                                                             \
  __builtin_amdgcn_s_setprio(1);                                               \
  _Pragma("unroll") for (int f = 0; f < 8; ++f)                                \
  _Pragma("unroll") for (int g = 0; g < 4; ++g)                                \
      acc[f][g] = __builtin_amdgcn_mfma_i32_16x16x64_i8(                       \
          AR[f], BR[g], acc[f][g], 0, 0, 0);                                   \
  __builtin_amdgcn_s_setprio(0);                                               \
  SB0();

  // ITER(kt): MFMA(kt) | stage A(kt+2) | load B(kt+2)->BRc | vmcnt(8):
  // A(kt+1)+B(kt+1) landed | barrier | ds_read frags(kt+1) -> ARn
#define ITER(SNXT, SSTG, ARc, BRc, ARn)                                        \
  do {                                                                         \
    asm volatile("s_waitcnt lgkmcnt(0)" ::: "memory");                         \
    SB0();                                                                     \
    MM(ARc, BRc)                                                               \
    {                                                                          \
      const int _kk = kk2 < NKT ? kk2 : NKT - 1;                               \
      STAGE(SSTG, (size_t)_kk * BK)                                            \
      LDB(BRc, _kk)                                                            \
    }                                                                          \
    SB0();                                                                     \
    asm volatile("s_waitcnt vmcnt(8)" ::: "memory");                           \
    __builtin_amdgcn_s_barrier();                                              \
    RDF(ARn, SNXT)                                                             \
    SB0();                                                                     \
    ++kk2;                                                                     \
  } while (0)

  i32x4 acc[8][4] = {};
  i32x4 arA[8], arB[8], brA[4], brB[4];

  signed char* s0 = lds;
  signed char* s1 = lds + 16384;
  signed char* s2 = lds + 32768;

  // prologue: stage A tiles 0,1; load B tiles 0,1; wait A0,A1,B0 (leave B1)
  STAGE(s0, 0)
  STAGE(s1, (size_t)BK)
  LDB(brA, 0)
  LDB(brB, 1)
  int kk2 = 2;
  asm volatile("s_waitcnt vmcnt(4)" ::: "memory");
  __builtin_amdgcn_s_barrier();
  RDF(arA, s0)
  SB0();

  signed char* sC = s0;
  signed char* sN = s1;
  signed char* sS = s2;
  for (int kt = 0; kt < NKT; kt += 2) {
    ITER(sN, sS, arA, brA, arB);
    ITER(sS, sC, arB, brB, arA);
    signed char* t = sC; sC = sS; sS = sN; sN = t;
  }

  // ---- epilogue: y = acc * (SX*scale[col]) + bias[col] ----
#pragma unroll
  for (int g = 0; g < 4; ++g) {
    const int col = (int)rowB0 + wn * 64 + g * 16 + lr;
    const float scv = SX * scale[col];
    const float bs = bias[col];
#pragma unroll
    for (int f = 0; f < 8; ++f) {
      const size_t r0 = rowA0 + (size_t)(wm * 128 + f * 16 + lg * 4);
#pragma unroll
      for (int rr = 0; rr < 4; ++rr) {
        __builtin_nontemporal_store((float)acc[f][g][rr] * scv + bs,
                                    &C[(r0 + rr) * (size_t)N + col]);
      }
    }
  }
#undef STAGE
#undef RDF
#undef LDB
#undef MM
#undef ITER
}

extern "C" void kernel_launch(void* const* d_in, const int* in_sizes, int n_in,
                              void* d_out, int out_size, void* d_ws, size_t ws_size,
                              hipStream_t stream) {
  (void)n_in; (void)out_size; (void)ws_size;
  const float* x = (const float*)d_in[0];
  const float* wgt = (const float*)d_in[1];
  const float* bias = (const float*)d_in[2];
  float* y = (float*)d_out;

  const int OUT = in_sizes[2];
  const int IN = in_sizes[1] / OUT;
  const int B = in_sizes[0] / IN;

  signed char* tern = (signed char*)d_ws;                                   // 64 MB frag-order
  signed char* xb = (signed char*)((char*)d_ws + (size_t)OUT * IN);         // 32 MB row-major
  float* scale = (float*)((char*)d_ws + (size_t)OUT * IN + (size_t)B * IN);

  quant_kernel<<<OUT, 256, 0, stream>>>(wgt, (uint4*)tern, scale, IN);

  const size_t n4 = (size_t)B * IN / 4;
  cvt_kernel<<<(unsigned)((n4 + 1023) / 1024), 256, 0, stream>>>(x, (unsigned*)xb, n4);

  gemm_kernel<<<(B / BM) * (OUT / BN), 256, 0, stream>>>(
      xb, (const i32x4*)tern, scale, bias, y, B, OUT, IN);
}

// Round 15
// 667.120 us; speedup vs baseline: 1.0268x; 1.0268x over previous
//
#include <hip/hip_runtime.h>
#include <stdint.h>

#define TFAC 0.05f
#define BM 256
#define BN 128
#define BK 64
#define XCLIP 6.0f
#define SX (XCLIP / 127.0f)

typedef __attribute__((ext_vector_type(4))) int i32x4;

static __device__ __forceinline__ unsigned pack4(int b0, int b1, int b2, int b3) {
  return (unsigned)(unsigned char)b0 | ((unsigned)(unsigned char)b1 << 8) |
         ((unsigned)(unsigned char)b2 << 16) | ((unsigned)(unsigned char)b3 << 24);
}

static __device__ __forceinline__ int q8(float v, float inv) {
  return (int)rintf(fminf(fmaxf(v * inv, -127.f), 127.f));
}

// ---- weight quantization -> ternary i8 in MFMA FRAGMENT ORDER + f32 scale ----
// (r12-verified) B'[(n>>4)*NKT + kt][lane][16B], lane = (n&15) + 16*((k>>4)&3)
__global__ __launch_bounds__(256) void quant_kernel(
    const float* __restrict__ W, uint4* __restrict__ T,
    float* __restrict__ scale, int IN) {
  const int row = blockIdx.x;
  const int t = threadIdx.x;
  const float4* wr = reinterpret_cast<const float4*>(W + (size_t)row * IN);

  float4 v[4];
  float s = 0.f;
#pragma unroll
  for (int i = 0; i < 4; ++i) {
    v[i] = wr[t * 4 + i];
    s += fabsf(v[i].x) + fabsf(v[i].y) + fabsf(v[i].z) + fabsf(v[i].w);
  }
#pragma unroll
  for (int off = 1; off < 64; off <<= 1) s += __shfl_xor(s, off);
  __shared__ float red[4];
  if ((t & 63) == 0) red[t >> 6] = s;
  __syncthreads();
  const float tot = red[0] + red[1] + red[2] + red[3];
  const float thr = TFAC * tot / (float)IN;

  float cnt = 0.f, ms = 0.f;
  unsigned u[4];
#pragma unroll
  for (int i = 0; i < 4; ++i) {
    float e[4] = {v[i].x, v[i].y, v[i].z, v[i].w};
    int o[4];
#pragma unroll
    for (int j = 0; j < 4; ++j) {
      const float a = fabsf(e[j]);
      const bool m = a > thr;
      cnt += m ? 1.f : 0.f;
      ms += m ? a : 0.f;
      o[j] = m ? (e[j] > 0.f ? 1 : -1) : 0;
    }
    u[i] = pack4(o[0], o[1], o[2], o[3]);
  }
  const int k64 = IN >> 6;
  const size_t idx = ((size_t)(row >> 4) * k64 + (t >> 2)) * 64 +
                     (size_t)(((t & 3) << 4) + (row & 15));
  T[idx] = make_uint4(u[0], u[1], u[2], u[3]);

#pragma unroll
  for (int off = 1; off < 64; off <<= 1) {
    cnt += __shfl_xor(cnt, off);
    ms += __shfl_xor(ms, off);
  }
  __shared__ float rc[4], rm[4];
  if ((t & 63) == 0) { rc[t >> 6] = cnt; rm[t >> 6] = ms; }
  __syncthreads();
  if (t == 0) {
    const float c = rc[0] + rc[1] + rc[2] + rc[3];
    const float m = rm[0] + rm[1] + rm[2] + rm[3];
    scale[row] = m / fmaxf(c, 1.f);
  }
}

// ---- x f32 -> i8 in A FRAGMENT ORDER via LDS transpose ----
// A'[(m>>4)*NKT + kt][lane][16B], lane = (m&15) + 16*((k>>4)&3).
// Block: one 16-row m-block x 2048 k-cols (half of K). LDS [16][129] uint4.
__global__ __launch_bounds__(256) void cvt_kernel(
    const float* __restrict__ X, uint4* __restrict__ A2, int K) {
  __shared__ uint4 lt[16 * 129];  // 33 KiB, row pitch 129 chunks (bank floor)
  const int t = (int)threadIdx.x;
  const int nh = K >> 11;                 // 2048-col halves
  const int bid = (int)blockIdx.x;
  const int mb = bid / nh;
  const int half = bid % nh;
  const int kf0 = half << 11;             // f32 col offset
  const float inv = 127.0f / XCLIP;

  // phase 1: coalesced read + convert + LDS write (16 rows x 128 chunks)
#pragma unroll
  for (int i = 0; i < 8; ++i) {
    const int cid = i * 256 + t;          // 0..2047
    const int row = cid >> 7;             // 0..15
    const int c = cid & 127;              // chunk within row
    const float4* src = reinterpret_cast<const float4*>(
        X + ((size_t)mb * 16 + row) * (size_t)K + kf0 + c * 16);
    unsigned u[4];
#pragma unroll
    for (int q = 0; q < 4; ++q) {
      const float4 a = src[q];
      u[q] = pack4(q8(a.x, inv), q8(a.y, inv), q8(a.z, inv), q8(a.w, inv));
    }
    lt[row * 129 + c] = make_uint4(u[0], u[1], u[2], u[3]);
  }
  __syncthreads();

  // phase 2: fragment-order readout, coalesced 16B stores
  const int NKT = K >> 6;
  const int kt0 = half << 5;              // 32 K-tiles per half
#pragma unroll
  for (int i = 0; i < 8; ++i) {
    const int flat = i * 256 + t;         // 0..2047
    const int ktl = flat >> 6;            // 0..31
    const int lane = flat & 63;
    const uint4 v = lt[(lane & 15) * 129 + ktl * 4 + (lane >> 4)];
    A2[((size_t)mb * NKT + kt0 + ktl) * 64 + lane] = v;
  }
}

// ---- 256x128 i8 NT GEMM: ZERO LDS, ZERO barriers. Both operands loaded
// ---- direct-to-reg from fragment order; compiler-managed waits; free waves.
__global__ __launch_bounds__(256, 2) void gemm_kernel(
    const i32x4* __restrict__ Aq,         // x i8, A fragment order
    const i32x4* __restrict__ Bq,         // tern i8, B fragment order
    const float* __restrict__ scale,      // [N]
    const float* __restrict__ bias,       // [N]
    float* __restrict__ C,                // [M][N]
    int M, int N, int K) {
  const int tid = (int)threadIdx.x;
  const int lane = tid & 63;
  const int w = tid >> 6;   // 0..3
  const int wm = w >> 1;    // 0..1 : 128-row half of A
  const int wn = w & 1;     // 0..1 : 64-col half of B
  const int lr = lane & 15;
  const int lg = lane >> 4;

  // XCD swizzle with intra-XCD 8-wide bn bands (r9/r11/r12-verified)
  const int nbm = M / BM;             // 32
  const int nbn = N / BN;             // 128
  const int nwg = nbm * nbn;
  const int jpx = nwg >> 3;
  const int rows8 = nbm * 8;
  const int nband = jpx / rows8;
  const int bid = (int)blockIdx.x;
  const int xcd = bid & 7;
  const int j = bid >> 3;
  const int band = j / rows8;
  const int r = j % rows8;
  const int bm = r >> 3;
  const int bn = (xcd * nband + band) * 8 + (r & 7);
  const size_t rowA0 = (size_t)bm * BM;
  const size_t rowB0 = (size_t)bn * BN;

  const int NKT = K / BK;             // 64

  // fragment bases: frag (block, kt) is 64 x 16B; lane-linear -> coalesced 1KB
  const i32x4* Af = Aq + ((size_t)(bm * 16 + wm * 8) * NKT) * 64 + lane;
  const i32x4* Bf = Bq + ((size_t)(bn * 8 + wn * 4) * NKT) * 64 + lane;

#define LDA(AR, KT)                                                            \
  _Pragma("unroll") for (int f = 0; f < 8; ++f)                                \
      AR[f] = Af[((size_t)f * NKT + (size_t)(KT)) * 64];

#define LDB(BR, KT)                                                            \
  _Pragma("unroll") for (int g = 0; g < 4; ++g)                                \
      BR[g] = Bf[((size_t)g * NKT + (size_t)(KT)) * 64];

#define MM(AR, BR)                                                             \
  __builtin_amdgcn_s_setprio(1);                                               \
  _Pragma("unroll") for (int f = 0; f < 8; ++f)                                \
  _Pragma("unroll") for (int g = 0; g < 4; ++g)                                \
      acc[f][g] = __builtin_amdgcn_mfma_i32_16x16x64_i8(                       \
          AR[f], BR[g], acc[f][g], 0, 0, 0);                                   \
  __builtin_amdgcn_s_setprio(0);

  i32x4 acc[8][4] = {};
  i32x4 arA[8], brA[4], arB[8], brB[4];

  LDA(arA, 0)
  LDB(brA, 0)
  for (int kt = 0; kt < NKT; kt += 2) {
    const int k1 = kt + 1 < NKT ? kt + 1 : NKT - 1;
    const int k2 = kt + 2 < NKT ? kt + 2 : NKT - 1;
    LDA(arB, k1)
    LDB(brB, k1)
    MM(arA, brA)
    LDA(arA, k2)
    LDB(brA, k2)
    MM(arB, brB)
  }

  // ---- epilogue: y = acc * (SX*scale[col]) + bias[col] ----
#pragma unroll
  for (int g = 0; g < 4; ++g) {
    const int col = (int)rowB0 + wn * 64 + g * 16 + lr;
    const float scv = SX * scale[col];
    const float bs = bias[col];
#pragma unroll
    for (int f = 0; f < 8; ++f) {
      const size_t r0 = rowA0 + (size_t)(wm * 128 + f * 16 + lg * 4);
#pragma unroll
      for (int rr = 0; rr < 4; ++rr) {
        __builtin_nontemporal_store((float)acc[f][g][rr] * scv + bs,
                                    &C[(r0 + rr) * (size_t)N + col]);
      }
    }
  }
#undef LDA
#undef LDB
#undef MM
}

extern "C" void kernel_launch(void* const* d_in, const int* in_sizes, int n_in,
                              void* d_out, int out_size, void* d_ws, size_t ws_size,
                              hipStream_t stream) {
  (void)n_in; (void)out_size; (void)ws_size;
  const float* x = (const float*)d_in[0];
  const float* wgt = (const float*)d_in[1];
  const float* bias = (const float*)d_in[2];
  float* y = (float*)d_out;

  const int OUT = in_sizes[2];
  const int IN = in_sizes[1] / OUT;
  const int B = in_sizes[0] / IN;

  signed char* tern = (signed char*)d_ws;                                   // B' frag order
  signed char* xb = (signed char*)((char*)d_ws + (size_t)OUT * IN);         // A' frag order
  float* scale = (float*)((char*)d_ws + (size_t)OUT * IN + (size_t)B * IN);

  quant_kernel<<<OUT, 256, 0, stream>>>(wgt, (uint4*)tern, scale, IN);

  const int nh = IN >> 11;
  cvt_kernel<<<(B / 16) * nh, 256, 0, stream>>>(x, (uint4*)xb, IN);

  gemm_kernel<<<(B / BM) * (OUT / BN), 256, 0, stream>>>(
      (const i32x4*)xb, (const i32x4*)tern, scale, bias, y, B, OUT, IN);
}